// Round 3
// baseline (588.046 us; speedup 1.0000x reference)
//
#include <hip/hip_runtime.h>
#include <hip/hip_bf16.h>

// ---------------- problem constants ----------------
#define BATCH 16
#define LAT 16
#define HID 512
#define NFC 16
#define START_ 4097
#define NSFC 2
#define NMESH 262144
#define JTOT 131104            // SFC*NFC*START = 2*65552
#define HB_BR_STRIDE 1048832   // BATCH*NFC*START

// conv chain logical / padded-stride lengths
#define L1 16385
#define L1S 16388
#define L2 65537
#define L3 262144

// per-branch buffer sizes (floats)
#define Y1_SZ (BATCH*8*L1S)    // 2,097,664
#define Y3_SZ (BATCH*L3)       // 4,194,304  ([N][B] transposed layout)

// exact identity tanh(x) = 1 - 2/(exp2(2x*log2e)+1); v_exp_f32 + v_rcp_f32, ~4 insts
__device__ __forceinline__ float tanh_fast(float x) {
    float e = __builtin_amdgcn_exp2f(x * 2.8853900817779268f);
    return 1.0f - 2.0f * __builtin_amdgcn_rcpf(e + 1.0f);
}

// ---------------- fc1: [16,16]@[16,512] + tanh ----------------
__global__ __launch_bounds__(256) void k_fc1(const float* __restrict__ x,
                                             const float* __restrict__ w,
                                             const float* __restrict__ bias,
                                             float* __restrict__ h1) {
    int j = blockIdx.x * 256 + threadIdx.x;   // < 512
    float acc[BATCH];
    float bv = bias[j];
#pragma unroll
    for (int b = 0; b < BATCH; ++b) acc[b] = bv;
#pragma unroll
    for (int k = 0; k < LAT; ++k) {
        float wv = w[k * HID + j];            // coalesced
#pragma unroll
        for (int b = 0; b < BATCH; ++b)
            acc[b] = fmaf(x[b * LAT + k], wv, acc[b]);  // x: uniform -> s_load
    }
#pragma unroll
    for (int b = 0; b < BATCH; ++b) h1[b * HID + j] = tanh_fast(acc[b]);
}

// ---------------- fc2: [16,512]@[512,131104] + tanh, branch-split store ----------------
__global__ __launch_bounds__(256) void k_fc2(const float* __restrict__ h1,
                                             const float* __restrict__ w,
                                             const float* __restrict__ bias,
                                             float* __restrict__ hb) {
    int j = blockIdx.x * 256 + threadIdx.x;
    if (j >= JTOT) return;
    float acc[BATCH];
    float bv = bias[j];
#pragma unroll
    for (int b = 0; b < BATCH; ++b) acc[b] = bv;
#pragma unroll 8
    for (int k = 0; k < HID; ++k) {
        float wv = w[(size_t)k * JTOT + j];   // coalesced HBM stream (268 MB)
#pragma unroll
        for (int b = 0; b < BATCH; ++b)
            acc[b] = fmaf(h1[b * HID + k], wv, acc[b]);  // uniform -> s_load
    }
    int i = j & 1;
    int s = j >> 1;
    int c = s / START_;
    int t = s - c * START_;
    float* hp = hb + (size_t)i * HB_BR_STRIDE + c * START_ + t;
#pragma unroll
    for (int b = 0; b < BATCH; ++b)
        hp[(size_t)b * (NFC * START_)] = tanh_fast(acc[b]);
}

// ---------------- ConvTranspose1d layer 1 (gather form) + tanh ----------------
// y[b,co,t] = bias[co] + sum_{d=0..7} sum_ci x[b,ci,q-d] * w[ci,co,4d+r],
// q=(t+16)>>2, r=(t+16)&3.  Lane owns 16 consecutive t (4 q's x r=0..3) so the
// weight index is wave-uniform (co fixed per wave) -> scalar loads.
template <int CIN, int COUT, int WCO, int WT>
__global__ __launch_bounds__(256) void k_conv(const float* __restrict__ xb,
                                              float* __restrict__ yb,
                                              const float* __restrict__ w0g,
                                              const float* __restrict__ w1g,
                                              const float* __restrict__ b0g,
                                              const float* __restrict__ b1g,
                                              int LIN, int LINS, int LOUT, int LOUTS,
                                              int xbs, int ybs) {
    constexpr int SROW = WT * 256 + 12;
    constexpr int SROW4 = SROW / 4;
    __shared__ __align__(16) float sx[CIN * SROW];

    const int br = blockIdx.z;
    const float* x = xb + (size_t)br * xbs;
    float* y = yb + (size_t)br * ybs;
    const float* wg = br ? w1g : w0g;
    const float* bg = br ? b1g : b0g;
    const int b = blockIdx.y;
    const int t0 = blockIdx.x * (WT * 1024);
    const int q0 = (t0 + 16) >> 2;

    for (int idx = threadIdx.x; idx < CIN * SROW; idx += 256) {
        int ci = idx / SROW;
        int sr = idx - ci * SROW;
        int s = q0 - 8 + sr;
        sx[idx] = (s >= 0 && s < LIN) ? x[(size_t)(b * CIN + ci) * LINS + s] : 0.f;
    }
    __syncthreads();

    const int wv = __builtin_amdgcn_readfirstlane((int)(threadIdx.x >> 6));
    const int lane = threadIdx.x & 63;
    constexpr int WAVES_CO = 4 / WT;
    const int wt = wv / WAVES_CO;
    const int co0 = (wv % WAVES_CO) * WCO;

    float acc[WCO][16];
#pragma unroll
    for (int cw = 0; cw < WCO; ++cw) {
        float bv = bg[co0 + cw];
#pragma unroll
        for (int e = 0; e < 16; ++e) acc[cw][e] = bv;
    }

    const int qrel4 = wt * 64 + lane;
    const float4* sx4 = (const float4*)sx;
#pragma unroll 1
    for (int ci = 0; ci < CIN; ++ci) {
        float4 A = sx4[ci * SROW4 + qrel4];
        float4 Bv = sx4[ci * SROW4 + qrel4 + 1];
        float4 Cv = sx4[ci * SROW4 + qrel4 + 2];
        float xv[12] = {A.x, A.y, A.z, A.w, Bv.x, Bv.y, Bv.z, Bv.w,
                        Cv.x, Cv.y, Cv.z, Cv.w};
        const float* wp = wg + (ci * COUT + co0) * 32;
#pragma unroll
        for (int cw = 0; cw < WCO; ++cw) {
            const float* wpc = wp + cw * 32;
#pragma unroll
            for (int d = 0; d < 8; ++d)
#pragma unroll
                for (int m = 0; m < 4; ++m)
#pragma unroll
                    for (int j = 0; j < 4; ++j)
                        acc[cw][m * 4 + j] =
                            fmaf(xv[m + 8 - d], wpc[4 * d + j], acc[cw][m * 4 + j]);
        }
    }

    const int t_lane = t0 + wt * 1024 + lane * 16;
#pragma unroll
    for (int cw = 0; cw < WCO; ++cw) {
        float* yp = y + (size_t)(b * COUT + co0 + cw) * LOUTS + t_lane;
        if (t_lane + 15 < LOUT) {
#pragma unroll
            for (int c4 = 0; c4 < 4; ++c4) {
                float4 o;
                o.x = tanh_fast(acc[cw][c4 * 4 + 0]);
                o.y = tanh_fast(acc[cw][c4 * 4 + 1]);
                o.z = tanh_fast(acc[cw][c4 * 4 + 2]);
                o.w = tanh_fast(acc[cw][c4 * 4 + 3]);
                ((float4*)yp)[c4] = o;
            }
        } else {
            for (int e = 0; e < 16; ++e)
                if (t_lane + e < LOUT) yp[e] = tanh_fast(acc[cw][e]);
        }
    }
}

// ---------------- fused ConvTranspose1d layers 2+3, batch-transposed output ----------
// Per block: branch br, 256-t y3 tile, all 16 batches.
//   stage A: load y1 window [16 b][8 ci][25 q]  (q = T0/16-4 .. +20) from global
//   stage B: compute y2 window [16 b][4 c][72]  (s2 = 64bx-4 .. 64bx+67) in LDS,
//            out-of-range s2 stored as 0 (matches transposed-conv zero padding)
//   stage C: conv3 from LDS y2 (conv3t structure), write y3t[t*16+b]
#define F_Y1W 25
#define F_Y2W 73               // 72 used + 1 pad (odd stride)

__global__ __launch_bounds__(256) void k_conv23t(const float* __restrict__ y1g,
                                                 float* __restrict__ y3t,
                                                 const float* __restrict__ w20,
                                                 const float* __restrict__ w21,
                                                 const float* __restrict__ b20,
                                                 const float* __restrict__ b21,
                                                 const float* __restrict__ w30,
                                                 const float* __restrict__ w31,
                                                 const float* __restrict__ b30,
                                                 const float* __restrict__ b31,
                                                 int xbs, int ybs) {
    __shared__ float s_y1[BATCH * 8 * F_Y1W];   // 12.8 KB
    __shared__ float s_y2[BATCH * 4 * F_Y2W];   // 18.7 KB

    const int br = blockIdx.z;
    const float* x1 = y1g + (size_t)br * xbs;
    float* y = y3t + (size_t)br * ybs;
    const float* w2 = br ? w21 : w20;
    const float b2v_all = 0.f; (void)b2v_all;
    const float* b2 = br ? b21 : b20;
    const float* w3 = br ? w31 : w30;
    const float b3v = (br ? b31 : b30)[0];

    const int bx = blockIdx.x;          // 1024 tiles of 256 t
    const int T0 = bx * 256;
    const int Q1_0 = (T0 >> 4) - 4;     // y1 window start (16bx-4), 25 values
    const int S2_0 = (T0 >> 2) - 4;     // s2 at s_y2 offset 0 = 64bx-4

    // ---- stage A: y1 window -> LDS ----
    for (int idx = threadIdx.x; idx < BATCH * 8 * F_Y1W; idx += 256) {
        int row = idx / F_Y1W;          // b*8 + ci
        int col = idx - row * F_Y1W;
        int q1 = Q1_0 + col;
        s_y1[idx] = (q1 >= 0 && q1 < L1) ? x1[(size_t)row * L1S + q1] : 0.f;
    }
    __syncthreads();

    // ---- stage B: y2 window in LDS ----
    // g2 = 16bx-1+g, g in [0,18): s2 = 4*g2+r = 64bx-4+4g+r -> s_y2 offset 4g+r
    // taps: y1[g2+4-d] = xv[7-d], xv[j] = s_y1[... Q1_0 + g + j]
    {
        const int wv = __builtin_amdgcn_readfirstlane((int)(threadIdx.x >> 6)); // c2
        const int lane = threadIdx.x & 63;
        const int b = lane & 15;
        const int gg = lane >> 4;
        const float b2v = b2[wv];
#pragma unroll
        for (int j5 = 0; j5 < 5; ++j5) {
            int g = gg + 4 * j5;
            if (g < 18) {
                float acc[4];
#pragma unroll
                for (int r = 0; r < 4; ++r) acc[r] = b2v;
#pragma unroll
                for (int ci = 0; ci < 8; ++ci) {
                    const float* sp = s_y1 + (b * 8 + ci) * F_Y1W + g;
                    float xv[8];
#pragma unroll
                    for (int jj = 0; jj < 8; ++jj) xv[jj] = sp[jj];
                    const float* wpc = w2 + (ci * 4 + wv) * 32;
#pragma unroll
                    for (int d = 0; d < 8; ++d)
#pragma unroll
                        for (int r = 0; r < 4; ++r)
                            acc[r] = fmaf(xv[7 - d], wpc[4 * d + r], acc[r]);
                }
                int s2b = S2_0 + 4 * g;          // s2 = s2b + r
                float* dst = s_y2 + (b * 4 + wv) * F_Y2W + 4 * g;
#pragma unroll
                for (int r = 0; r < 4; ++r) {
                    int s2 = s2b + r;
                    dst[r] = (s2 >= 0 && s2 < L2) ? tanh_fast(acc[r]) : 0.f;
                }
            }
        }
    }
    __syncthreads();

    // ---- stage C: conv3 from LDS y2 (conv3t structure) ----
    // thread: q = tid>>2 (0..63), bg = tid&3; t = T0 + 4q + r
    // taps s3 = (T0/4+4+q) - d; s_y2 offset = s3 - S2_0 = q + 1 + (7-d)
    {
        const int q = threadIdx.x >> 2;
        const int bg = threadIdx.x & 3;

        float acc[4][4];                 // [r][bo]
#pragma unroll
        for (int r = 0; r < 4; ++r)
#pragma unroll
            for (int bo = 0; bo < 4; ++bo) acc[r][bo] = b3v;

#pragma unroll
        for (int ci = 0; ci < 4; ++ci) {
            const float* wp = w3 + ci * 32;   // wave-uniform
#pragma unroll
            for (int bo = 0; bo < 4; ++bo) {
                const float* sp = s_y2 + ((bg * 4 + bo) * 4 + ci) * F_Y2W + q + 1;
                float xv[8];
#pragma unroll
                for (int j = 0; j < 8; ++j) xv[j] = sp[j];
#pragma unroll
                for (int d = 0; d < 8; ++d)
#pragma unroll
                    for (int r = 0; r < 4; ++r)
                        acc[r][bo] = fmaf(xv[7 - d], wp[4 * d + r], acc[r][bo]);
            }
        }

        const int tbase = T0 + 4 * q;
#pragma unroll
        for (int r = 0; r < 4; ++r) {
            float* yp = y + (size_t)(tbase + r) * BATCH + bg * 4;
            float4 o;
            o.x = tanh_fast(acc[r][0]);
            o.y = tanh_fast(acc[r][1]);
            o.z = tanh_fast(acc[r][2]);
            o.w = tanh_fast(acc[r][3]);
            *(float4*)yp = o;
        }
    }
}

// ---------------- final: one-shot 64B-chunk gather + 3-tap stencil + combine ----------------
__global__ __launch_bounds__(256) void k_final(const float* __restrict__ y3t0,
                                               const float* __restrict__ y3t1,
                                               const int* __restrict__ ord0,
                                               const int* __restrict__ ord1,
                                               const float* __restrict__ sw0,
                                               const float* __restrict__ sb0,
                                               const float* __restrict__ sw1,
                                               const float* __restrict__ sb1,
                                               const float* __restrict__ fw,
                                               const float* __restrict__ fb,
                                               float* __restrict__ out) {
    __shared__ int i0[258], i1[258];
    __shared__ float c0[BATCH][264], c1[BATCH][264];   // [b][jj], ~34 KB
    const int tid = threadIdx.x;
    const int n0 = blockIdx.x * 256;
    const int n = n0 + tid;

    for (int jj = tid; jj < 258; jj += 256) {
        int nn = n0 - 1 + jj;
        nn = nn < 0 ? 0 : (nn > NMESH - 1 ? NMESH - 1 : nn);
        i0[jj] = ord0[nn];
        i1[jj] = ord1[nn];
    }
    __syncthreads();

    // gather all 16 batches per index: 4 float4 per index, every fetched byte used
    for (int kk = tid; kk < 258 * 4; kk += 256) {
        int jj = kk >> 2;
        int v = kk & 3;
        float4 a = *(const float4*)(y3t0 + (size_t)i0[jj] * BATCH + v * 4);
        c0[v * 4 + 0][jj] = a.x;
        c0[v * 4 + 1][jj] = a.y;
        c0[v * 4 + 2][jj] = a.z;
        c0[v * 4 + 3][jj] = a.w;
        float4 bq = *(const float4*)(y3t1 + (size_t)i1[jj] * BATCH + v * 4);
        c1[v * 4 + 0][jj] = bq.x;
        c1[v * 4 + 1][jj] = bq.y;
        c1[v * 4 + 2][jj] = bq.z;
        c1[v * 4 + 3][jj] = bq.w;
    }

    const float w00 = sw0[n * 3], w01 = sw0[n * 3 + 1], w02 = sw0[n * 3 + 2];
    const float w10 = sw1[n * 3], w11 = sw1[n * 3 + 1], w12 = sw1[n * 3 + 2];
    const float s0b = sb0[n], s1b = sb1[n];
    const float f0 = fw[n * 2], f1 = fw[n * 2 + 1], fbv = fb[n];
    __syncthreads();

#pragma unroll
    for (int b = 0; b < BATCH; ++b) {
        float z0 = tanh_fast(w00 * c0[b][tid] + w01 * c0[b][tid + 1] + w02 * c0[b][tid + 2] + s0b);
        float z1 = tanh_fast(w10 * c1[b][tid] + w11 * c1[b][tid + 1] + w12 * c1[b][tid + 2] + s1b);
        out[b * NMESH + n] = tanh_fast(f0 * z0 + f1 * z1 + fbv);
    }
}

// ---------------- launch ----------------
extern "C" void kernel_launch(void* const* d_in, const int* in_sizes, int n_in,
                              void* d_out, int out_size, void* d_ws, size_t ws_size,
                              hipStream_t stream) {
    const float* x     = (const float*)d_in[0];
    const float* fc1_w = (const float*)d_in[1];
    const float* fc1_b = (const float*)d_in[2];
    const float* fc2_w = (const float*)d_in[3];
    const float* fc2_b = (const float*)d_in[4];
    const float* ctw[2][3] = {{(const float*)d_in[5], (const float*)d_in[7], (const float*)d_in[9]},
                              {(const float*)d_in[16], (const float*)d_in[18], (const float*)d_in[20]}};
    const float* ctb[2][3] = {{(const float*)d_in[6], (const float*)d_in[8], (const float*)d_in[10]},
                              {(const float*)d_in[17], (const float*)d_in[19], (const float*)d_in[21]}};
    const float* sp0w = (const float*)d_in[11];
    const float* sp0b = (const float*)d_in[12];
    const int*   ord0 = (const int*)d_in[13];
    const float* sp1w = (const float*)d_in[22];
    const float* sp1b = (const float*)d_in[23];
    const int*   ord1 = (const int*)d_in[24];
    const float* fspw = (const float*)d_in[27];
    const float* fspb = (const float*)d_in[28];
    float* out = (float*)d_out;
    float* ws = (float*)d_ws;

    // workspace layout (floats)
    const size_t OFF_H1 = 0;
    const size_t OFF_HB = 8192;
    // parallel-branch layout
    const size_t OFF_Y1p = OFF_HB + 2ull * HB_BR_STRIDE;        // 2,105,856
    const size_t OFF_Y3p = OFF_Y1p + 2ull * Y1_SZ;              // 6,301,184
    const size_t END_P = OFF_Y3p + 2ull * Y3_SZ;                // 14,689,792
    // serial layout (shared y1 scratch)
    const size_t OFF_Y1s = OFF_HB + 2ull * HB_BR_STRIDE;
    const size_t OFF_Y3s = OFF_Y1s + (size_t)Y1_SZ;

    const bool par = ws_size >= END_P * sizeof(float);

    k_fc1<<<2, 256, 0, stream>>>(x, fc1_w, fc1_b, ws + OFF_H1);
    k_fc2<<<(JTOT + 255) / 256, 256, 0, stream>>>(ws + OFF_H1, fc2_w, fc2_b, ws + OFF_HB);

    float* y3_0;
    float* y3_1;
    if (par) {
        float* hb = ws + OFF_HB;
        float* y1 = ws + OFF_Y1p;
        float* y3 = ws + OFF_Y3p;
        k_conv<16, 8, 2, 1><<<dim3(17, BATCH, 2), 256, 0, stream>>>(
            hb, y1, ctw[0][0], ctw[1][0], ctb[0][0], ctb[1][0],
            START_, START_, L1, L1S, HB_BR_STRIDE, Y1_SZ);
        k_conv23t<<<dim3(L3 / 256, 1, 2), 256, 0, stream>>>(
            y1, y3, ctw[0][1], ctw[1][1], ctb[0][1], ctb[1][1],
            ctw[0][2], ctw[1][2], ctb[0][2], ctb[1][2],
            Y1_SZ, Y3_SZ);
        y3_0 = y3;
        y3_1 = y3 + Y3_SZ;
    } else {
        float* y1 = ws + OFF_Y1s;
        for (int i = 0; i < 2; ++i) {
            float* hb_i = ws + OFF_HB + (size_t)i * HB_BR_STRIDE;
            float* y3_i = ws + OFF_Y3s + (size_t)i * Y3_SZ;
            k_conv<16, 8, 2, 1><<<dim3(17, BATCH, 1), 256, 0, stream>>>(
                hb_i, y1, ctw[i][0], ctw[i][0], ctb[i][0], ctb[i][0],
                START_, START_, L1, L1S, 0, 0);
            k_conv23t<<<dim3(L3 / 256, 1, 1), 256, 0, stream>>>(
                y1, y3_i, ctw[i][1], ctw[i][1], ctb[i][1], ctb[i][1],
                ctw[i][2], ctw[i][2], ctb[i][2], ctb[i][2],
                0, 0);
        }
        y3_0 = ws + OFF_Y3s;
        y3_1 = ws + OFF_Y3s + Y3_SZ;
    }

    k_final<<<NMESH / 256, 256, 0, stream>>>(y3_0, y3_1, ord0, ord1,
                                             sp0w, sp0b, sp1w, sp1b,
                                             fspw, fspb, out);
}

// Round 4
// 554.581 us; speedup vs baseline: 1.0603x; 1.0603x over previous
//
#include <hip/hip_runtime.h>
#include <hip/hip_bf16.h>

// ---------------- problem constants ----------------
#define BATCH 16
#define LAT 16
#define HID 512
#define NFC 16
#define START_ 4097
#define NSFC 2
#define NMESH 262144
#define JTOT 131104            // SFC*NFC*START = 2*65552
#define HB_BR_STRIDE 1048832   // BATCH*NFC*START

// conv chain logical / padded-stride lengths
#define L1 16385
#define L1S 16388
#define L2 65537
#define L2S 65540
#define L3 262144

// per-branch buffer sizes (floats)
#define Y1_SZ (BATCH*8*L1S)    // 2,097,664
#define Y2_SZ (BATCH*4*L2S)    // 4,194,560
#define Y3_SZ (BATCH*L3)       // 4,194,304  ([N][B] transposed layout)

// exact identity tanh(x) = 1 - 2/(exp2(2x*log2e)+1); v_exp_f32 + v_rcp_f32, ~5 insts
// (validated round 3: absmax 1.22e-4, passed)
__device__ __forceinline__ float tanh_fast(float x) {
    float e = __builtin_amdgcn_exp2f(x * 2.8853900817779268f);
    return 1.0f - 2.0f * __builtin_amdgcn_rcpf(e + 1.0f);
}

// ---------------- fc1: [16,16]@[16,512] + tanh ----------------
__global__ __launch_bounds__(256) void k_fc1(const float* __restrict__ x,
                                             const float* __restrict__ w,
                                             const float* __restrict__ bias,
                                             float* __restrict__ h1) {
    int j = blockIdx.x * 256 + threadIdx.x;   // < 512
    float acc[BATCH];
    float bv = bias[j];
#pragma unroll
    for (int b = 0; b < BATCH; ++b) acc[b] = bv;
#pragma unroll
    for (int k = 0; k < LAT; ++k) {
        float wv = w[k * HID + j];            // coalesced
#pragma unroll
        for (int b = 0; b < BATCH; ++b)
            acc[b] = fmaf(x[b * LAT + k], wv, acc[b]);  // x: uniform -> s_load
    }
#pragma unroll
    for (int b = 0; b < BATCH; ++b) h1[b * HID + j] = tanh_fast(acc[b]);
}

// ---------------- fc2: [16,512]@[512,131104] + tanh, branch-split store ----------------
__global__ __launch_bounds__(256) void k_fc2(const float* __restrict__ h1,
                                             const float* __restrict__ w,
                                             const float* __restrict__ bias,
                                             float* __restrict__ hb) {
    int j = blockIdx.x * 256 + threadIdx.x;
    if (j >= JTOT) return;
    float acc[BATCH];
    float bv = bias[j];
#pragma unroll
    for (int b = 0; b < BATCH; ++b) acc[b] = bv;
#pragma unroll 8
    for (int k = 0; k < HID; ++k) {
        float wv = w[(size_t)k * JTOT + j];   // coalesced HBM stream (268 MB)
#pragma unroll
        for (int b = 0; b < BATCH; ++b)
            acc[b] = fmaf(h1[b * HID + k], wv, acc[b]);  // uniform -> s_load
    }
    int i = j & 1;
    int s = j >> 1;
    int c = s / START_;
    int t = s - c * START_;
    float* hp = hb + (size_t)i * HB_BR_STRIDE + c * START_ + t;
#pragma unroll
    for (int b = 0; b < BATCH; ++b)
        hp[(size_t)b * (NFC * START_)] = tanh_fast(acc[b]);
}

// ---------------- ConvTranspose1d (gather form) + tanh, layers 1-2 ----------------
// y[b,co,t] = bias[co] + sum_{d=0..7} sum_ci x[b,ci,q-d] * w[ci,co,4d+r],
// q=(t+16)>>2, r=(t+16)&3.  Lane owns 16 consecutive t (4 q's x r=0..3) so the
// weight index is wave-uniform (co fixed per wave) -> scalar loads.
template <int CIN, int COUT, int WCO, int WT>
__global__ __launch_bounds__(256) void k_conv(const float* __restrict__ xb,
                                              float* __restrict__ yb,
                                              const float* __restrict__ w0g,
                                              const float* __restrict__ w1g,
                                              const float* __restrict__ b0g,
                                              const float* __restrict__ b1g,
                                              int LIN, int LINS, int LOUT, int LOUTS,
                                              int xbs, int ybs) {
    constexpr int SROW = WT * 256 + 12;
    constexpr int SROW4 = SROW / 4;
    __shared__ __align__(16) float sx[CIN * SROW];

    const int br = blockIdx.z;
    const float* x = xb + (size_t)br * xbs;
    float* y = yb + (size_t)br * ybs;
    const float* wg = br ? w1g : w0g;
    const float* bg = br ? b1g : b0g;
    const int b = blockIdx.y;
    const int t0 = blockIdx.x * (WT * 1024);
    const int q0 = (t0 + 16) >> 2;

    for (int idx = threadIdx.x; idx < CIN * SROW; idx += 256) {
        int ci = idx / SROW;
        int sr = idx - ci * SROW;
        int s = q0 - 8 + sr;
        sx[idx] = (s >= 0 && s < LIN) ? x[(size_t)(b * CIN + ci) * LINS + s] : 0.f;
    }
    __syncthreads();

    const int wv = __builtin_amdgcn_readfirstlane((int)(threadIdx.x >> 6));
    const int lane = threadIdx.x & 63;
    constexpr int WAVES_CO = 4 / WT;
    const int wt = wv / WAVES_CO;
    const int co0 = (wv % WAVES_CO) * WCO;

    float acc[WCO][16];
#pragma unroll
    for (int cw = 0; cw < WCO; ++cw) {
        float bv = bg[co0 + cw];
#pragma unroll
        for (int e = 0; e < 16; ++e) acc[cw][e] = bv;
    }

    const int qrel4 = wt * 64 + lane;
    const float4* sx4 = (const float4*)sx;
#pragma unroll 1
    for (int ci = 0; ci < CIN; ++ci) {
        float4 A = sx4[ci * SROW4 + qrel4];
        float4 Bv = sx4[ci * SROW4 + qrel4 + 1];
        float4 Cv = sx4[ci * SROW4 + qrel4 + 2];
        float xv[12] = {A.x, A.y, A.z, A.w, Bv.x, Bv.y, Bv.z, Bv.w,
                        Cv.x, Cv.y, Cv.z, Cv.w};
        const float* wp = wg + (ci * COUT + co0) * 32;
#pragma unroll
        for (int cw = 0; cw < WCO; ++cw) {
            const float* wpc = wp + cw * 32;
#pragma unroll
            for (int d = 0; d < 8; ++d)
#pragma unroll
                for (int m = 0; m < 4; ++m)
#pragma unroll
                    for (int j = 0; j < 4; ++j)
                        acc[cw][m * 4 + j] =
                            fmaf(xv[m + 8 - d], wpc[4 * d + j], acc[cw][m * 4 + j]);
        }
    }

    const int t_lane = t0 + wt * 1024 + lane * 16;
#pragma unroll
    for (int cw = 0; cw < WCO; ++cw) {
        float* yp = y + (size_t)(b * COUT + co0 + cw) * LOUTS + t_lane;
        if (t_lane + 15 < LOUT) {
#pragma unroll
            for (int c4 = 0; c4 < 4; ++c4) {
                float4 o;
                o.x = tanh_fast(acc[cw][c4 * 4 + 0]);
                o.y = tanh_fast(acc[cw][c4 * 4 + 1]);
                o.z = tanh_fast(acc[cw][c4 * 4 + 2]);
                o.w = tanh_fast(acc[cw][c4 * 4 + 3]);
                ((float4*)yp)[c4] = o;
            }
        } else {
            for (int e = 0; e < 16; ++e)
                if (t_lane + e < LOUT) yp[e] = tanh_fast(acc[cw][e]);
        }
    }
}

// ---------------- ConvTranspose1d layer 3, batch-transposed output ----------------
// y3t[t*16 + b] = tanh(conv3(y2)[b,0,t]).  256-t tile per block, thread owns
// (q-group, batch-quad): q = tid>>2, bg = tid&3 -> acc[4 r][4 b] = 16 VGPRs only.
// Odd LDS row stride (71) => the 4 bg lanes at a given q alias 2-per-bank (free).
#define C3_TT 256
#define C3_SW 71                // window: q0-7 .. q0+63 inclusive = 71 floats

__global__ __launch_bounds__(256) void k_conv3t(const float* __restrict__ y2g,
                                                float* __restrict__ y3t,
                                                const float* __restrict__ w0g,
                                                const float* __restrict__ w1g,
                                                const float* __restrict__ b0g,
                                                const float* __restrict__ b1g,
                                                int xbs, int ybs) {
    __shared__ float sx[BATCH * 4 * C3_SW];   // [b][ci][s] 18.2 KB

    const int br = blockIdx.z;
    const float* x = y2g + (size_t)br * xbs;
    float* y = y3t + (size_t)br * ybs;
    const float* wg = br ? w1g : w0g;
    const float bv = (br ? b1g : b0g)[0];

    const int t0 = blockIdx.x * C3_TT;
    const int q0 = (t0 >> 2) + 4;        // (t0+16)>>2, t0 % 4 == 0
    const int s0 = q0 - 7;

    for (int idx = threadIdx.x; idx < BATCH * 4 * C3_SW; idx += 256) {
        int row = idx / C3_SW;           // b*4 + ci
        int col = idx - row * C3_SW;
        int s = s0 + col;
        sx[idx] = (s >= 0 && s < L2) ? x[(size_t)row * L2S + s] : 0.f;
    }
    __syncthreads();

    const int q = threadIdx.x >> 2;      // 0..63   (global q = q0 + q)
    const int bg = threadIdx.x & 3;      // batch quad: b = bg*4 + bo

    float acc[4][4];                     // [r][bo]
#pragma unroll
    for (int r = 0; r < 4; ++r)
#pragma unroll
        for (int bo = 0; bo < 4; ++bo) acc[r][bo] = bv;

#pragma unroll
    for (int ci = 0; ci < 4; ++ci) {
        const float* wp = wg + ci * 32;  // w[ci][0][k], COUT=1, wave-uniform
#pragma unroll
        for (int bo = 0; bo < 4; ++bo) {
            const float* sp = sx + ((bg * 4 + bo) * 4 + ci) * C3_SW + q;  // sp[j]=x[Q-7+j]
            float xv[8];
#pragma unroll
            for (int j = 0; j < 8; ++j) xv[j] = sp[j];
#pragma unroll
            for (int d = 0; d < 8; ++d)
#pragma unroll
                for (int r = 0; r < 4; ++r)
                    acc[r][bo] = fmaf(xv[7 - d], wp[4 * d + r], acc[r][bo]);
        }
    }

    // t = t0 + 4*q + r; thread writes float4 (4 batches) per r; the 4 bg lanes
    // at a given q fill one contiguous 64B sector per instruction.
    const int tbase = t0 + 4 * q;
#pragma unroll
    for (int r = 0; r < 4; ++r) {
        float* yp = y + (size_t)(tbase + r) * BATCH + bg * 4;
        float4 o;
        o.x = tanh_fast(acc[r][0]);
        o.y = tanh_fast(acc[r][1]);
        o.z = tanh_fast(acc[r][2]);
        o.w = tanh_fast(acc[r][3]);
        *(float4*)yp = o;
    }
}

// ---------------- final: one-shot 64B-chunk gather + 3-tap stencil + combine ----------------
__global__ __launch_bounds__(256) void k_final(const float* __restrict__ y3t0,
                                               const float* __restrict__ y3t1,
                                               const int* __restrict__ ord0,
                                               const int* __restrict__ ord1,
                                               const float* __restrict__ sw0,
                                               const float* __restrict__ sb0,
                                               const float* __restrict__ sw1,
                                               const float* __restrict__ sb1,
                                               const float* __restrict__ fw,
                                               const float* __restrict__ fb,
                                               float* __restrict__ out) {
    __shared__ int i0[258], i1[258];
    __shared__ float c0[BATCH][264], c1[BATCH][264];   // [b][jj], ~34 KB
    const int tid = threadIdx.x;
    const int n0 = blockIdx.x * 256;
    const int n = n0 + tid;

    for (int jj = tid; jj < 258; jj += 256) {
        int nn = n0 - 1 + jj;
        nn = nn < 0 ? 0 : (nn > NMESH - 1 ? NMESH - 1 : nn);
        i0[jj] = ord0[nn];
        i1[jj] = ord1[nn];
    }
    __syncthreads();

    // gather all 16 batches per index: 4 float4 per index, every fetched byte used
    for (int kk = tid; kk < 258 * 4; kk += 256) {
        int jj = kk >> 2;
        int v = kk & 3;
        float4 a = *(const float4*)(y3t0 + (size_t)i0[jj] * BATCH + v * 4);
        c0[v * 4 + 0][jj] = a.x;
        c0[v * 4 + 1][jj] = a.y;
        c0[v * 4 + 2][jj] = a.z;
        c0[v * 4 + 3][jj] = a.w;
        float4 bq = *(const float4*)(y3t1 + (size_t)i1[jj] * BATCH + v * 4);
        c1[v * 4 + 0][jj] = bq.x;
        c1[v * 4 + 1][jj] = bq.y;
        c1[v * 4 + 2][jj] = bq.z;
        c1[v * 4 + 3][jj] = bq.w;
    }

    const float w00 = sw0[n * 3], w01 = sw0[n * 3 + 1], w02 = sw0[n * 3 + 2];
    const float w10 = sw1[n * 3], w11 = sw1[n * 3 + 1], w12 = sw1[n * 3 + 2];
    const float s0b = sb0[n], s1b = sb1[n];
    const float f0 = fw[n * 2], f1 = fw[n * 2 + 1], fbv = fb[n];
    __syncthreads();

#pragma unroll
    for (int b = 0; b < BATCH; ++b) {
        float z0 = tanh_fast(w00 * c0[b][tid] + w01 * c0[b][tid + 1] + w02 * c0[b][tid + 2] + s0b);
        float z1 = tanh_fast(w10 * c1[b][tid] + w11 * c1[b][tid + 1] + w12 * c1[b][tid + 2] + s1b);
        out[b * NMESH + n] = tanh_fast(f0 * z0 + f1 * z1 + fbv);
    }
}

// ---------------- launch ----------------
extern "C" void kernel_launch(void* const* d_in, const int* in_sizes, int n_in,
                              void* d_out, int out_size, void* d_ws, size_t ws_size,
                              hipStream_t stream) {
    const float* x     = (const float*)d_in[0];
    const float* fc1_w = (const float*)d_in[1];
    const float* fc1_b = (const float*)d_in[2];
    const float* fc2_w = (const float*)d_in[3];
    const float* fc2_b = (const float*)d_in[4];
    const float* ctw[2][3] = {{(const float*)d_in[5], (const float*)d_in[7], (const float*)d_in[9]},
                              {(const float*)d_in[16], (const float*)d_in[18], (const float*)d_in[20]}};
    const float* ctb[2][3] = {{(const float*)d_in[6], (const float*)d_in[8], (const float*)d_in[10]},
                              {(const float*)d_in[17], (const float*)d_in[19], (const float*)d_in[21]}};
    const float* sp0w = (const float*)d_in[11];
    const float* sp0b = (const float*)d_in[12];
    const int*   ord0 = (const int*)d_in[13];
    const float* sp1w = (const float*)d_in[22];
    const float* sp1b = (const float*)d_in[23];
    const int*   ord1 = (const int*)d_in[24];
    const float* fspw = (const float*)d_in[27];
    const float* fspb = (const float*)d_in[28];
    float* out = (float*)d_out;
    float* ws = (float*)d_ws;

    // workspace layout (floats)
    const size_t OFF_H1 = 0;
    const size_t OFF_HB = 8192;
    // parallel-branch layout
    const size_t OFF_Y1p = OFF_HB + 2ull * HB_BR_STRIDE;        // 2,105,856
    const size_t OFF_Y2p = OFF_Y1p + 2ull * Y1_SZ;              // 6,301,184
    const size_t OFF_Y3p = OFF_Y2p + 2ull * Y2_SZ;              // 14,690,304
    const size_t END_P = OFF_Y3p + 2ull * Y3_SZ;                // 23,078,912
    // serial layout (shared conv scratch)
    const size_t OFF_Y1s = OFF_HB + 2ull * HB_BR_STRIDE;
    const size_t OFF_Y2s = OFF_Y1s + (size_t)Y1_SZ;
    const size_t OFF_Y3s = OFF_Y2s + (size_t)Y2_SZ;

    const bool par = ws_size >= END_P * sizeof(float);

    k_fc1<<<2, 256, 0, stream>>>(x, fc1_w, fc1_b, ws + OFF_H1);
    k_fc2<<<(JTOT + 255) / 256, 256, 0, stream>>>(ws + OFF_H1, fc2_w, fc2_b, ws + OFF_HB);

    float* y3_0;
    float* y3_1;
    if (par) {
        float* hb = ws + OFF_HB;
        float* y1 = ws + OFF_Y1p;
        float* y2 = ws + OFF_Y2p;
        float* y3 = ws + OFF_Y3p;
        k_conv<16, 8, 2, 1><<<dim3(17, BATCH, 2), 256, 0, stream>>>(
            hb, y1, ctw[0][0], ctw[1][0], ctb[0][0], ctb[1][0],
            START_, START_, L1, L1S, HB_BR_STRIDE, Y1_SZ);
        k_conv<8, 4, 1, 1><<<dim3(65, BATCH, 2), 256, 0, stream>>>(
            y1, y2, ctw[0][1], ctw[1][1], ctb[0][1], ctb[1][1],
            L1, L1S, L2, L2S, Y1_SZ, Y2_SZ);
        k_conv3t<<<dim3(L3 / C3_TT, 1, 2), 256, 0, stream>>>(
            y2, y3, ctw[0][2], ctw[1][2], ctb[0][2], ctb[1][2],
            Y2_SZ, Y3_SZ);
        y3_0 = y3;
        y3_1 = y3 + Y3_SZ;
    } else {
        float* y1 = ws + OFF_Y1s;
        float* y2 = ws + OFF_Y2s;
        for (int i = 0; i < 2; ++i) {
            float* hb_i = ws + OFF_HB + (size_t)i * HB_BR_STRIDE;
            float* y3_i = ws + OFF_Y3s + (size_t)i * Y3_SZ;
            k_conv<16, 8, 2, 1><<<dim3(17, BATCH, 1), 256, 0, stream>>>(
                hb_i, y1, ctw[i][0], ctw[i][0], ctb[i][0], ctb[i][0],
                START_, START_, L1, L1S, 0, 0);
            k_conv<8, 4, 1, 1><<<dim3(65, BATCH, 1), 256, 0, stream>>>(
                y1, y2, ctw[i][1], ctw[i][1], ctb[i][1], ctb[i][1],
                L1, L1S, L2, L2S, 0, 0);
            k_conv3t<<<dim3(L3 / C3_TT, 1, 1), 256, 0, stream>>>(
                y2, y3_i, ctw[i][2], ctw[i][2], ctb[i][2], ctb[i][2],
                0, 0);
        }
        y3_0 = ws + OFF_Y3s;
        y3_1 = ws + OFF_Y3s + Y3_SZ;
    }

    k_final<<<NMESH / 256, 256, 0, stream>>>(y3_0, y3_1, ord0, ord1,
                                             sp0w, sp0b, sp1w, sp1b,
                                             fspw, fspb, out);
}